// Round 16
// baseline (669.208 us; speedup 1.0000x reference)
//
#include <hip/hip_runtime.h>
#include <math.h>

// ---------------- dims ----------------
// T=S=48, H=250, EMB=300, gates=1000, 13 sim planes, convnet 48->24->12->6->3->1

typedef __attribute__((ext_vector_type(2))) _Float16 h2f;
typedef unsigned long long u64;

// workspace layout (floats)
#define OFF_XW    0            // 4*48*1000 = 192000 (bias pre-folded)
#define OFF_HS    192000       // 4*48*250  = 48000
#define OFF_SC    240000       // 13*2304 = 29952
#define OFF_BUFA  269952       // 73728 (conv1 out 128x24x24; conv3 out; conv5 out)
#define OFF_BUFB  343680       // 23616 (conv2 out 164x12x12; conv4 out)
#define OFF_WIHT  367296       // 600000 fp32 transposed w_ih [2][300][1000]
#define OFF_WPK   967296       // 250000 u32: packed fp16 w_hh [2][125][1000]
#define OFF_SEL   1217296      // 2*2304 bytes = 1152 floats
#define OFF_CNT   1218448      // 4 ints (grid barrier counter)
// total ~1218452 floats (~4.9 MB)

#define NBLK 256

__device__ __forceinline__ float sigf(float x) { return 1.f / (1.f + expf(-x)); }

#if __has_builtin(__builtin_amdgcn_fdot2)
__device__ __forceinline__ float dot2(h2f a, h2f b, float c) {
    return __builtin_amdgcn_fdot2(a, b, c, false);
}
#else
__device__ __forceinline__ float dot2(h2f a, h2f b, float c) {
    return c + (float)a.x * (float)b.x + (float)a.y * (float)b.y;
}
#endif

// grid-wide barrier: 1 block/CU co-residency guaranteed by grid=NBLK.
// Agent-scope acq-rel (mechanism validated in r2/r3 lstm cross-block exchange).
__device__ __forceinline__ void gridbar(int* cnt, int target) {
    __syncthreads();
    if (threadIdx.x == 0) {
        __hip_atomic_fetch_add(cnt, 1, __ATOMIC_ACQ_REL, __HIP_MEMORY_SCOPE_AGENT);
        while (__hip_atomic_load(cnt, __ATOMIC_ACQUIRE, __HIP_MEMORY_SCOPE_AGENT) < target) {
#if __has_builtin(__builtin_amdgcn_s_sleep)
            __builtin_amdgcn_s_sleep(2);
#endif
        }
    }
    __syncthreads();
}

// ---------------- 0) fused weight prep (+ zero grid-barrier counter) ----------------
// grid dim3(32, 10, 3), block dim3(32, 32)
__global__ void prep_kernel(const float* __restrict__ wihf, const float* __restrict__ wihb,
                            const float* __restrict__ whhf, const float* __restrict__ whhb,
                            float* __restrict__ wT, unsigned int* __restrict__ wpk,
                            int* __restrict__ cnt)
{
    if (blockIdx.x == 0 && blockIdx.y == 0 && blockIdx.z == 0 &&
        threadIdx.x == 0 && threadIdx.y == 0)
        __hip_atomic_store(cnt, 0, __ATOMIC_RELAXED, __HIP_MEMORY_SCOPE_AGENT);

    if (blockIdx.z < 2) {
        __shared__ float tile[32][33];
        int dir = blockIdx.z;
        const float* w = dir ? wihb : wihf;

        int j = blockIdx.x * 32 + threadIdx.y;   // row of w (0..999)
        int k = blockIdx.y * 32 + threadIdx.x;   // col of w (0..299)
        if (j < 1000 && k < 300)
            tile[threadIdx.y][threadIdx.x] = w[(size_t)j * 300 + k];
        __syncthreads();

        int ko = blockIdx.y * 32 + threadIdx.y;
        int jo = blockIdx.x * 32 + threadIdx.x;
        if (ko < 300 && jo < 1000)
            wT[(size_t)dir * 300000 + (size_t)ko * 1000 + jo] = tile[threadIdx.x][threadIdx.y];
    } else {
        if (blockIdx.y >= 8) return;
        __shared__ unsigned int ptile[32][33];
        int jt  = blockIdx.x;
        int pt  = blockIdx.y & 3;
        int dir = blockIdx.y >> 2;
        const float* w = dir ? whhb : whhf;

        int p = pt * 32 + threadIdx.x;
        int j = jt * 32 + threadIdx.y;
        if (p < 125 && j < 1000) {
            float2 v = *(const float2*)(w + (size_t)j * 250 + 2 * p);
            h2f pv; pv.x = (_Float16)v.x; pv.y = (_Float16)v.y;
            ptile[threadIdx.y][threadIdx.x] = *(unsigned int*)&pv;
        }
        __syncthreads();

        int jo = jt * 32 + threadIdx.x;
        int po = pt * 32 + threadIdx.y;
        if (po < 125 && jo < 1000)
            wpk[(size_t)dir * 125000 + (size_t)po * 1000 + jo] = ptile[threadIdx.x][threadIdx.y];
    }
}

// ---------------- 1) embedding gather + x @ w_ih^T + bias ----------------
__global__ void embed_xw_kernel(const int* __restrict__ x1, const int* __restrict__ x2,
                                const float* __restrict__ emb, const float* __restrict__ wT,
                                const float* __restrict__ b_f, const float* __restrict__ b_b,
                                float* __restrict__ xW)
{
    int t = blockIdx.x % 48;
    int m = blockIdx.x / 48;
    const int* x = (m < 2) ? x1 : x2;
    const float* w = wT + (size_t)(m & 1) * 300000;
    const float* bias = (m & 1) ? b_b : b_f;

    __shared__ float e[300];
    int row = x[t];
    for (int k = threadIdx.x; k < 300; k += 512)
        e[k] = emb[(size_t)row * 300 + k];
    __syncthreads();

    int j0 = threadIdx.x;
    int j1 = threadIdx.x + 512;
    int j1c = j1 < 1000 ? j1 : 999;
    float a0 = 0.f, a1 = 0.f;
    #pragma unroll 4
    for (int k = 0; k < 300; ++k) {
        float ek = e[k];
        const float* wr = w + (size_t)k * 1000;
        a0 += ek * wr[j0];
        a1 += ek * wr[j1c];
    }
    float* out = xW + ((size_t)m * 48 + t) * 1000;
    out[j0] = a0 + bias[j0];
    if (j1 < 1000) out[j1] = a1 + bias[j1];
}

// ---------------- 2) LSTM: r13 structure (106us floor for this decomposition) ----------------
__global__ void __launch_bounds__(512, 1) lstm_kernel(
    const float* __restrict__ xW, const unsigned int* __restrict__ wpk,
    float* __restrict__ hs)
{
    int m   = blockIdx.x;
    int dir = m & 1;
    const unsigned int* wp = wpk + (size_t)dir * 125000;
    const float* xw = xW + (size_t)m * 48000;
    float* out      = hs + (size_t)m * 12000;

    int t = threadIdx.x;
    bool active = t < 500;
    int r0 = t, r1 = t + 500;

    __shared__ __align__(16) unsigned int hp[128];
    __shared__ float fo_lds[500];
    __shared__ __align__(16) uint4 wl4[3 * 1000];

    for (int idx = t; idx < 3000; idx += 512) {
        int q = idx / 1000, r = idx % 1000;
        uint4 v;
        v.x = wp[(4 * q + 0) * 1000 + r];
        v.y = wp[(4 * q + 1) * 1000 + r];
        v.z = wp[(4 * q + 2) * 1000 + r];
        v.w = wp[(4 * q + 3) * 1000 + r];
        wl4[idx] = v;
    }

    h2f w0r[113], w1r[113];
    if (active) {
        #pragma unroll
        for (int p = 0; p < 113; ++p) {
            unsigned int a = wp[(p + 12) * 1000 + r0];
            unsigned int b = wp[(p + 12) * 1000 + r1];
            w0r[p] = *(h2f*)&a;
            w1r[p] = *(h2f*)&b;
        }
    }
    if (t < 128) hp[t] = 0u;
    float c = 0.f;

    int tt = dir ? 47 : 0;
    float px0 = 0.f, px1 = 0.f;
    if (active) {
        px0 = xw[tt * 1000 + r0];
        px1 = xw[tt * 1000 + r1];
    }
    __syncthreads();

    for (int step = 0; step < 48; ++step) {
        int ttn = dir ? 46 - step : step + 1;
        float n0 = 0.f, n1 = 0.f;
        if (active && step < 47) {
            n0 = xw[ttn * 1000 + r0];
            n1 = xw[ttn * 1000 + r1];
        }
        float a0 = 0.f, a1 = 0.f;
        if (active) {
            float a0e = px0, a0o = 0.f, a1e = px1, a1o = 0.f;
            const uint4* hp4 = (const uint4*)hp;
            #pragma unroll
            for (int q = 0; q < 3; ++q) {
                uint4 hq = hp4[q];
                h2f h0 = *(h2f*)&hq.x, h1 = *(h2f*)&hq.y, h2v = *(h2f*)&hq.z, h3 = *(h2f*)&hq.w;
                uint4 wv0 = wl4[q * 1000 + r0];
                uint4 wv1 = wl4[q * 1000 + r1];
                a0e = dot2(*(h2f*)&wv0.x, h0, a0e);  a1e = dot2(*(h2f*)&wv1.x, h0, a1e);
                a0o = dot2(*(h2f*)&wv0.y, h1, a0o);  a1o = dot2(*(h2f*)&wv1.y, h1, a1o);
                a0e = dot2(*(h2f*)&wv0.z, h2v, a0e); a1e = dot2(*(h2f*)&wv1.z, h2v, a1e);
                a0o = dot2(*(h2f*)&wv0.w, h3, a0o);  a1o = dot2(*(h2f*)&wv1.w, h3, a1o);
            }
            #pragma unroll
            for (int jj = 3; jj < 31; ++jj) {
                uint4 hq = hp4[jj];
                h2f h0 = *(h2f*)&hq.x, h1 = *(h2f*)&hq.y, h2v = *(h2f*)&hq.z, h3 = *(h2f*)&hq.w;
                int p = 4 * jj - 12;
                a0e = dot2(w0r[p + 0], h0, a0e);  a1e = dot2(w1r[p + 0], h0, a1e);
                a0o = dot2(w0r[p + 1], h1, a0o);  a1o = dot2(w1r[p + 1], h1, a1o);
                a0e = dot2(w0r[p + 2], h2v, a0e); a1e = dot2(w1r[p + 2], h2v, a1e);
                a0o = dot2(w0r[p + 3], h3, a0o);  a1o = dot2(w1r[p + 3], h3, a1o);
            }
            {
                unsigned int hq = hp[124];
                h2f hv = *(h2f*)&hq;
                a0e = dot2(w0r[112], hv, a0e);
                a1e = dot2(w1r[112], hv, a1e);
            }
            a0 = a0e + a0o;
            a1 = a1e + a1o;
            if (t >= 250) {
                fo_lds[t - 250] = sigf(a0);
                fo_lds[250 + (t - 250)] = sigf(a1);
            }
        }
        __syncthreads();
        if (t < 250) {
            float iv = sigf(a0);
            float gv = tanhf(a1);
            float fv = fo_lds[t];
            float ov = fo_lds[250 + t];
            c = fv * c + iv * gv;
            float hn = ov * tanhf(c);
            out[tt * 250 + t] = hn;
            float hi = __shfl_down(hn, 1);
            if (!(t & 1)) {
                h2f pv; pv.x = (_Float16)hn; pv.y = (_Float16)hi;
                hp[t >> 1] = *(unsigned int*)&pv;
            }
        }
        px0 = n0; px1 = n1; tt = ttn;
        __syncthreads();
    }
}

// ---------------- conv tile body (shared by conv2..conv5 stages) ----------------
// Block-wide: all threads call (syncs uniform); act guards work. sm needs 576+P floats.
__device__ __forceinline__ void conv_tile(const float* __restrict__ in, const float* __restrict__ w,
    const float* __restrict__ bias, float* __restrict__ out, float* sm, int t, bool act,
    int Cin, int H, int W, int tileH, int tileW, int ty0, int tx0,
    int cpc, int CC, int pk, int ps, int PHf, int PWf, int co)
{
    int P = tileH * tileW;
    int pix = t % P, chunk = t / P;
    int y = ty0 + pix / tileW, x = tx0 + pix % tileW;
    float acc = 0.f;
    if (act && chunk < CC) {
        int c0 = chunk * cpc, c1 = c0 + cpc; if (c1 > Cin) c1 = Cin;
        const float* wco = w + (size_t)co * Cin * 9;
        for (int ci = c0; ci < c1; ++ci) {
            const float* inp = in + (size_t)ci * H * W;
            const float* wp = wco + (size_t)ci * 9;
            #pragma unroll
            for (int ky = 0; ky < 3; ++ky) {
                int iy = y + ky - 1;
                if (iy < 0 || iy >= H) continue;
                const float* rowp = inp + iy * W;
                #pragma unroll
                for (int kx = 0; kx < 3; ++kx) {
                    int ix = x + kx - 1;
                    if (ix < 0 || ix >= W) continue;
                    acc += rowp[ix] * wp[ky * 3 + kx];
                }
            }
        }
    }
    sm[t] = acc;
    __syncthreads();
    if (act && chunk == 0) {
        float tot = bias[co];
        for (int cc2 = 0; cc2 < CC; ++cc2) tot += sm[pix + cc2 * P];
        sm[576 + pix] = tot > 0.f ? tot : 0.f;
    }
    __syncthreads();
    int pH = (tileH - pk) / ps + 1, pW = (tileW - pk) / ps + 1;
    if (act && t < pH * pW) {
        int py = t / pW, px = t % pW;
        float best = -INFINITY;
        for (int dy = 0; dy < pk; ++dy)
            for (int dx = 0; dx < pk; ++dx) {
                float v = sm[576 + (py * ps + dy) * tileW + (px * ps + dx)];
                best = v > best ? v : best;
            }
        out[((size_t)co * PHf + (ty0 / ps + py)) * PWf + (tx0 / ps + px)] = best;
    }
    __syncthreads();
}

// ---------------- 3) persistent tail: sim -> greedy -> conv1..conv5 -> head ----------------
// 256 blocks (1/CU, co-resident) x 576 threads; 7 grid barriers replace 7 kernel launches.
__global__ void __launch_bounds__(576) tail_kernel(
    const float* __restrict__ hs, float* __restrict__ sc, unsigned char* __restrict__ sel,
    const float* __restrict__ c1_w, const float* __restrict__ c1_b,
    const float* __restrict__ c2_w, const float* __restrict__ c2_b,
    const float* __restrict__ c3_w, const float* __restrict__ c3_b,
    const float* __restrict__ c4_w, const float* __restrict__ c4_b,
    const float* __restrict__ c5_w, const float* __restrict__ c5_b,
    const float* __restrict__ dnn_w, const float* __restrict__ dnn_b,
    const float* __restrict__ out_w, const float* __restrict__ out_b,
    float* __restrict__ bufA, float* __restrict__ bufB,
    int* __restrict__ cnt, float* __restrict__ outp)
{
    __shared__ float sm[720];
    __shared__ unsigned char selL[2304];
    int t = threadIdx.x;
    int b = blockIdx.x;

    // ---- stage 1: sim (2304 pairs = 256 blocks x 9 waves) ----
    {
        int wave = t >> 6, lane = t & 63;
        int p = b * 9 + wave;
        int i = p / 48, jj = p % 48;
        const float* h1f = hs + ((size_t)0 * 48 + i) * 250;
        const float* h1b = hs + ((size_t)1 * 48 + i) * 250;
        const float* h2f = hs + ((size_t)2 * 48 + jj) * 250;
        const float* h2b = hs + ((size_t)3 * 48 + jj) * 250;
        float dff = 0.f, dbb = 0.f, dfb = 0.f, dbf = 0.f;
        float sfa = 0.f, sba = 0.f, caa = 0.f;
        float sfb = 0.f, sbb = 0.f, cbb = 0.f;
        for (int k = lane; k < 250; k += 64) {
            float af = h1f[k], ab = h1b[k], bf = h2f[k], bb = h2b[k];
            dff += af * bf; dbb += ab * bb; dfb += af * bb; dbf += ab * bf;
            sfa += af * af; sba += ab * ab; caa += af * ab;
            sfb += bf * bf; sbb += bb * bb; cbb += bf * bb;
        }
        #pragma unroll
        for (int o = 32; o; o >>= 1) {
            dff += __shfl_down(dff, o); dbb += __shfl_down(dbb, o);
            dfb += __shfl_down(dfb, o); dbf += __shfl_down(dbf, o);
            sfa += __shfl_down(sfa, o); sba += __shfl_down(sba, o);
            caa += __shfl_down(caa, o);
            sfb += __shfl_down(sfb, o); sbb += __shfl_down(sbb, o);
            cbb += __shfl_down(cbb, o);
        }
        if (lane == 0) {
            #define EMIT(basep, dotv, sa2, sb2)                                 \
            {                                                                   \
                float na = sqrtf(sa2), nbv = sqrtf(sb2);                        \
                float dv = (dotv);                                              \
                sc[(basep) * 2304 + p] = dv;                                    \
                sc[((basep) + 1) * 2304 + p] = dv / (na * nbv + 1e-8f);         \
                float d2 = fmaxf(na * na + nbv * nbv - 2.f * dv, 1e-12f);       \
                sc[((basep) + 2) * 2304 + p] = sqrtf(d2);                       \
            }
            EMIT(0, dff + dbb, sfa + sba, sfb + sbb);
            EMIT(3, dff, sfa, sfb);
            EMIT(6, dbb, sba, sbb);
            EMIT(9, dff + dfb + dbf + dbb, sfa + sba + 2.f * caa, sfb + sbb + 2.f * cbb);
            #undef EMIT
        }
    }
    gridbar(cnt, NBLK * 1);

    // ---- stage 2: greedy top-k (blocks 0,1; single wave each, no internal syncs) ----
    if (b < 2 && t < 64) {
        int lane = t;
        int plane = 10 + b;
        u64 v[36];
        #pragma unroll
        for (int q = 0; q < 36; ++q) {
            int i = lane + 64 * q;
            unsigned int u = __float_as_uint(sc[plane * 2304 + i]);
            unsigned int ord = (u & 0x80000000u) ? ~u : (u | 0x80000000u);
            v[q] = ((u64)ord << 32) | (unsigned int)(4095 - i);
            selL[i] = 0;
        }
        #pragma unroll
        for (int a = 0; a < 35; ++a) {
            #pragma unroll
            for (int bb2 = 0; bb2 < 35 - a; ++bb2) {
                u64 lo = v[bb2] < v[bb2 + 1] ? v[bb2] : v[bb2 + 1];
                u64 hi = v[bb2] < v[bb2 + 1] ? v[bb2 + 1] : v[bb2];
                v[bb2] = hi; v[bb2 + 1] = lo;
            }
        }
        u64 m1 = 0, m2 = 0;
        for (int it = 0; it < 96; ++it) {
            u64 bv = v[0];
            #pragma unroll
            for (int o = 1; o < 64; o <<= 1) {
                u64 ov = __shfl_xor(bv, o);
                if (ov > bv) bv = ov;
            }
            int idx = 4095 - (int)(bv & 0xFFFFFFFFu);
            int p1 = idx / 48, p2 = idx % 48;
            bool ok = !((m1 >> p1) & 1) && !((m2 >> p2) & 1);
            if (ok) { m1 |= 1ull << p1; m2 |= 1ull << p2; }
            if (v[0] == bv) {
                if (ok) selL[idx] = 1;
                #pragma unroll
                for (int q = 0; q < 35; ++q) v[q] = v[q + 1];
                v[35] = 0;
            }
        }
        for (int q = 0; q < 36; ++q) {
            int i = lane + 64 * q;
            sel[b * 2304 + i] = selL[i];
        }
    }
    gridbar(cnt, NBLK * 2);

    // ---- stage 3: conv1 + mask + relu + pool (1152 jobs; 2 x 256-thread sub-jobs/block) ----
    for (int iter = 0; iter < 3; ++iter) {
        int sub = t >> 8;            // 0,1 active; 2 idle (t>=512)
        int ltid = t & 255;
        int job = iter * 512 + b * 2 + sub;
        bool act = (sub < 2) && (job < 1152);
        float r = 0.f;
        int co = 0, ty0 = 0, tx0 = 0;
        if (act) {
            co = job / 9;
            int tl = job % 9;
            ty0 = (tl / 3) * 16; tx0 = (tl % 3) * 16;
            int tx = ltid % 16, ty = ltid / 16;
            int x = tx0 + tx, y = ty0 + ty;
            float mv[9];
            #pragma unroll
            for (int ky = 0; ky < 3; ++ky) {
                int iy = y + ky - 1;
                #pragma unroll
                for (int kx = 0; kx < 3; ++kx) {
                    int ix = x + kx - 1;
                    float mm = 0.f;
                    if (iy >= 0 && iy < 48 && ix >= 0 && ix < 48) {
                        int p = iy * 48 + ix;
                        mm = (sel[p] | sel[2304 + p]) ? 1.0f : 0.1f;
                    }
                    mv[ky * 3 + kx] = mm;
                }
            }
            float acc = c1_b[co];
            const float* wco = c1_w + (size_t)co * 13 * 9;
            for (int ci = 0; ci < 12; ++ci) {
                const float* inp = sc + (size_t)ci * 2304;
                const float* wp = wco + ci * 9;
                #pragma unroll
                for (int ky = 0; ky < 3; ++ky) {
                    int iy = y + ky - 1;
                    if (iy < 0 || iy >= 48) continue;
                    #pragma unroll
                    for (int kx = 0; kx < 3; ++kx) {
                        int ix = x + kx - 1;
                        if (ix < 0 || ix >= 48) continue;
                        acc += inp[iy * 48 + ix] * mv[ky * 3 + kx] * wp[ky * 3 + kx];
                    }
                }
            }
            r = acc > 0.f ? acc : 0.f;
        }
        if (sub < 2) sm[sub * 256 + ltid] = r;
        __syncthreads();
        if (act && ltid < 64) {
            int py = ltid / 8, px = ltid % 8;
            float* tile = sm + sub * 256;
            float a = tile[(py * 2) * 16 + px * 2];
            float bb2 = tile[(py * 2) * 16 + px * 2 + 1];
            float cc = tile[(py * 2 + 1) * 16 + px * 2];
            float d = tile[(py * 2 + 1) * 16 + px * 2 + 1];
            float best = fmaxf(fmaxf(a, bb2), fmaxf(cc, d));
            bufA[(size_t)co * 576 + (ty0 / 2 + py) * 24 + (tx0 / 2 + px)] = best;
        }
        __syncthreads();
    }
    gridbar(cnt, NBLK * 3);

    // ---- stage 4: conv2 (656 jobs = 164 co x 2x2 tiles; 3 iters) ----
    for (int iter = 0; iter < 3; ++iter) {
        int job = iter * 256 + b;
        bool act = job < 656;
        int co = job >> 2, tyi = (job >> 1) & 1, txi = job & 1;
        conv_tile(bufA, c2_w, c2_b, bufB, sm, t, act,
                  128, 24, 24, 12, 12, tyi * 12, txi * 12, 32, 4, 2, 2, 12, 12, co);
    }
    gridbar(cnt, NBLK * 4);

    // ---- stage 5: conv3 (192 jobs) ----
    conv_tile(bufB, c3_w, c3_b, bufA, sm, t, b < 192,
              164, 12, 12, 12, 12, 0, 0, 41, 4, 2, 2, 6, 6, b);
    gridbar(cnt, NBLK * 5);

    // ---- stage 6: conv4 (192 jobs) ----
    conv_tile(bufA, c4_w, c4_b, bufB, sm, t, b < 192,
              192, 6, 6, 6, 6, 0, 0, 12, 16, 2, 2, 3, 3, b);
    gridbar(cnt, NBLK * 6);

    // ---- stage 7: conv5 (128 jobs) ----
    conv_tile(bufB, c5_w, c5_b, bufA, sm, t, b < 128,
              192, 3, 3, 3, 3, 0, 0, 3, 64, 3, 1, 1, 1, b);
    gridbar(cnt, NBLK * 7);

    // ---- stage 8: head (block 0 only; others exit) ----
    if (b != 0) return;
    if (t < 128) {
        float a = dnn_b[t];
        for (int k = 0; k < 128; ++k) a += bufA[k] * dnn_w[t * 128 + k];
        sm[t] = a > 0.f ? a : 0.f;
    }
    __syncthreads();
    if (t < 5) {
        float a = out_b[t];
        for (int k = 0; k < 128; ++k) a += sm[k] * out_w[t * 128 + k];
        sm[128 + t] = a;
    }
    __syncthreads();
    if (t == 0) {
        float mx = sm[128];
        for (int l = 1; l < 5; ++l) mx = fmaxf(mx, sm[128 + l]);
        float s = 0.f;
        for (int l = 0; l < 5; ++l) s += expf(sm[128 + l] - mx);
        float lse = logf(s);
        for (int l = 0; l < 5; ++l) outp[l] = sm[128 + l] - mx - lse;
    }
}

extern "C" void kernel_launch(void* const* d_in, const int* in_sizes, int n_in,
                              void* d_out, int out_size, void* d_ws, size_t ws_size,
                              hipStream_t stream)
{
    const int*   x1     = (const int*)d_in[0];
    const int*   x2     = (const int*)d_in[1];
    const float* emb    = (const float*)d_in[2];
    const float* w_ih_f = (const float*)d_in[3];
    const float* w_hh_f = (const float*)d_in[4];
    const float* b_f    = (const float*)d_in[5];
    const float* w_ih_b = (const float*)d_in[6];
    const float* w_hh_b = (const float*)d_in[7];
    const float* b_b    = (const float*)d_in[8];
    const float* c1_w   = (const float*)d_in[9];
    const float* c1_b   = (const float*)d_in[10];
    const float* c2_w   = (const float*)d_in[11];
    const float* c2_b   = (const float*)d_in[12];
    const float* c3_w   = (const float*)d_in[13];
    const float* c3_b   = (const float*)d_in[14];
    const float* c4_w   = (const float*)d_in[15];
    const float* c4_b   = (const float*)d_in[16];
    const float* c5_w   = (const float*)d_in[17];
    const float* c5_b   = (const float*)d_in[18];
    const float* dnn_w  = (const float*)d_in[19];
    const float* dnn_b  = (const float*)d_in[20];
    const float* out_w  = (const float*)d_in[21];
    const float* out_b  = (const float*)d_in[22];

    float* ws    = (float*)d_ws;
    float* xW    = ws + OFF_XW;
    float* hsb   = ws + OFF_HS;
    float* sc    = ws + OFF_SC;
    float* bufA  = ws + OFF_BUFA;
    float* bufB  = ws + OFF_BUFB;
    float* wihT  = ws + OFF_WIHT;
    unsigned int* wpk = (unsigned int*)(ws + OFF_WPK);
    unsigned char* sel = (unsigned char*)(ws + OFF_SEL);
    int*   cnt   = (int*)(ws + OFF_CNT);
    float* outp  = (float*)d_out;

    prep_kernel<<<dim3(32, 10, 3), dim3(32, 32), 0, stream>>>(
        w_ih_f, w_ih_b, w_hh_f, w_hh_b, wihT, wpk, cnt);
    embed_xw_kernel<<<192, 512, 0, stream>>>(x1, x2, emb, wihT, b_f, b_b, xW);
    lstm_kernel<<<4, 512, 0, stream>>>(xW, wpk, hsb);
    tail_kernel<<<NBLK, 576, 0, stream>>>(
        hsb, sc, sel, c1_w, c1_b, c2_w, c2_b, c3_w, c3_b, c4_w, c4_b, c5_w, c5_b,
        dnn_w, dnn_b, out_w, out_b, bufA, bufB, cnt, outp);
}

// Round 17
// 344.966 us; speedup vs baseline: 1.9399x; 1.9399x over previous
//
#include <hip/hip_runtime.h>
#include <math.h>

// ---------------- dims ----------------
// T=S=48, H=250, EMB=300, gates=1000, 13 sim planes, convnet 48->24->12->6->3->1

typedef __attribute__((ext_vector_type(2))) _Float16 h2f;
typedef unsigned long long u64;

// workspace layout (floats)
#define OFF_XW    0            // 4*48*1000 = 192000 (bias pre-folded)
#define OFF_HS    192000       // 4*48*250  = 48000
#define OFF_SC    240000       // 13*2304 = 29952
#define OFF_BUFA  269952       // 73728 (conv1 out 128x24x24; conv3 out; conv5 out)
#define OFF_BUFB  343680       // 23616 (conv2 out 164x12x12; conv4 out)
#define OFF_WIHT  367296       // 600000 fp32 transposed w_ih [2][300][1000]
#define OFF_WPK   967296       // 250000 u32: packed fp16 w_hh [2][125][1000]
#define OFF_SEL   1217296      // 2*2304 bytes = 1152 floats
// total ~1218448 floats (~4.9 MB)

__device__ __forceinline__ float sigf(float x) { return 1.f / (1.f + expf(-x)); }

#if __has_builtin(__builtin_amdgcn_fdot2)
__device__ __forceinline__ float dot2(h2f a, h2f b, float c) {
    return __builtin_amdgcn_fdot2(a, b, c, false);
}
#else
__device__ __forceinline__ float dot2(h2f a, h2f b, float c) {
    return c + (float)a.x * (float)b.x + (float)a.y * (float)b.y;
}
#endif

// ---------------- 0) fused weight prep ----------------
// grid dim3(32, 10, 3), block dim3(32, 32)
// z<2: tiled transpose w_ih[dir]: [1000][300] -> [300][1000]
// z==2: LDS-tiled pack w_hh -> fp16 pairs [dir][pair][row]
__global__ void prep_kernel(const float* __restrict__ wihf, const float* __restrict__ wihb,
                            const float* __restrict__ whhf, const float* __restrict__ whhb,
                            float* __restrict__ wT, unsigned int* __restrict__ wpk)
{
    if (blockIdx.z < 2) {
        __shared__ float tile[32][33];
        int dir = blockIdx.z;
        const float* w = dir ? wihb : wihf;

        int j = blockIdx.x * 32 + threadIdx.y;   // row of w (0..999)
        int k = blockIdx.y * 32 + threadIdx.x;   // col of w (0..299)
        if (j < 1000 && k < 300)
            tile[threadIdx.y][threadIdx.x] = w[(size_t)j * 300 + k];
        __syncthreads();

        int ko = blockIdx.y * 32 + threadIdx.y;
        int jo = blockIdx.x * 32 + threadIdx.x;
        if (ko < 300 && jo < 1000)
            wT[(size_t)dir * 300000 + (size_t)ko * 1000 + jo] = tile[threadIdx.x][threadIdx.y];
    } else {
        // pack: tiles of 32 j-rows x 32 pairs, bounced through LDS
        if (blockIdx.y >= 8) return;
        __shared__ unsigned int ptile[32][33];
        int jt  = blockIdx.x;            // j-tile 0..31
        int pt  = blockIdx.y & 3;        // pair-tile 0..3
        int dir = blockIdx.y >> 2;       // 0..1
        const float* w = dir ? whhb : whhf;

        int p = pt * 32 + threadIdx.x;
        int j = jt * 32 + threadIdx.y;
        if (p < 125 && j < 1000) {
            float2 v = *(const float2*)(w + (size_t)j * 250 + 2 * p);
            h2f pv; pv.x = (_Float16)v.x; pv.y = (_Float16)v.y;
            ptile[threadIdx.y][threadIdx.x] = *(unsigned int*)&pv;
        }
        __syncthreads();

        int jo = jt * 32 + threadIdx.x;
        int po = pt * 32 + threadIdx.y;
        if (po < 125 && jo < 1000)
            wpk[(size_t)dir * 125000 + (size_t)po * 1000 + jo] = ptile[threadIdx.x][threadIdx.y];
    }
}

// ---------------- 1) embedding gather + x @ w_ih^T + bias (coalesced via wT) ----------------
__global__ void embed_xw_kernel(const int* __restrict__ x1, const int* __restrict__ x2,
                                const float* __restrict__ emb, const float* __restrict__ wT,
                                const float* __restrict__ b_f, const float* __restrict__ b_b,
                                float* __restrict__ xW)
{
    int t = blockIdx.x % 48;
    int m = blockIdx.x / 48;
    const int* x = (m < 2) ? x1 : x2;
    const float* w = wT + (size_t)(m & 1) * 300000;
    const float* bias = (m & 1) ? b_b : b_f;

    __shared__ float e[300];
    int row = x[t];
    for (int k = threadIdx.x; k < 300; k += 512)
        e[k] = emb[(size_t)row * 300 + k];
    __syncthreads();

    int j0 = threadIdx.x;
    int j1 = threadIdx.x + 512;
    int j1c = j1 < 1000 ? j1 : 999;
    float a0 = 0.f, a1 = 0.f;
    #pragma unroll 4
    for (int k = 0; k < 300; ++k) {
        float ek = e[k];
        const float* wr = w + (size_t)k * 1000;
        a0 += ek * wr[j0];
        a1 += ek * wr[j1c];
    }
    float* out = xW + ((size_t)m * 48 + t) * 1000;
    out[j0] = a0 + bias[j0];
    if (j1 < 1000) out[j1] = a1 + bias[j1];
}

// ---------------- 2) LSTM: one block per (seq,dir), 512 threads = 8 waves ----------------
// r13 structure (106us floor for this decomposition): thread t<500 owns rows {t, t+500};
// weight pairs 0..11 in LDS quads, 12..124 in regs; xW prefetch; 2 barriers/step.
__global__ void __launch_bounds__(512, 1) lstm_kernel(
    const float* __restrict__ xW, const unsigned int* __restrict__ wpk,
    float* __restrict__ hs)
{
    int m   = blockIdx.x;           // 0: s1 fwd, 1: s1 bwd, 2: s2 fwd, 3: s2 bwd
    int dir = m & 1;
    const unsigned int* wp = wpk + (size_t)dir * 125000;
    const float* xw = xW + (size_t)m * 48000;
    float* out      = hs + (size_t)m * 12000;

    int t = threadIdx.x;
    bool active = t < 500;
    int r0 = t, r1 = t + 500;

    __shared__ __align__(16) unsigned int hp[128];     // packed fp16 h pairs
    __shared__ float fo_lds[500];                      // fv [0..249], ov [250..499]
    __shared__ __align__(16) uint4 wl4[3 * 1000];      // weight pairs 0..11 as quads [q][row]

    for (int idx = t; idx < 3000; idx += 512) {
        int q = idx / 1000, r = idx % 1000;
        uint4 v;
        v.x = wp[(4 * q + 0) * 1000 + r];
        v.y = wp[(4 * q + 1) * 1000 + r];
        v.z = wp[(4 * q + 2) * 1000 + r];
        v.w = wp[(4 * q + 3) * 1000 + r];
        wl4[idx] = v;
    }

    h2f w0r[113], w1r[113];
    if (active) {
        #pragma unroll
        for (int p = 0; p < 113; ++p) {
            unsigned int a = wp[(p + 12) * 1000 + r0];
            unsigned int b = wp[(p + 12) * 1000 + r1];
            w0r[p] = *(h2f*)&a;
            w1r[p] = *(h2f*)&b;
        }
    }
    if (t < 128) hp[t] = 0u;
    float c = 0.f;

    int tt = dir ? 47 : 0;
    float px0 = 0.f, px1 = 0.f;
    if (active) {
        px0 = xw[tt * 1000 + r0];
        px1 = xw[tt * 1000 + r1];
    }
    __syncthreads();

    for (int step = 0; step < 48; ++step) {
        int ttn = dir ? 46 - step : step + 1;
        float n0 = 0.f, n1 = 0.f;
        if (active && step < 47) {
            n0 = xw[ttn * 1000 + r0];
            n1 = xw[ttn * 1000 + r1];
        }
        float a0 = 0.f, a1 = 0.f;
        if (active) {
            float a0e = px0, a0o = 0.f, a1e = px1, a1o = 0.f;
            const uint4* hp4 = (const uint4*)hp;
            #pragma unroll
            for (int q = 0; q < 3; ++q) {
                uint4 hq = hp4[q];
                h2f h0 = *(h2f*)&hq.x, h1 = *(h2f*)&hq.y, h2v = *(h2f*)&hq.z, h3 = *(h2f*)&hq.w;
                uint4 wv0 = wl4[q * 1000 + r0];
                uint4 wv1 = wl4[q * 1000 + r1];
                a0e = dot2(*(h2f*)&wv0.x, h0, a0e);  a1e = dot2(*(h2f*)&wv1.x, h0, a1e);
                a0o = dot2(*(h2f*)&wv0.y, h1, a0o);  a1o = dot2(*(h2f*)&wv1.y, h1, a1o);
                a0e = dot2(*(h2f*)&wv0.z, h2v, a0e); a1e = dot2(*(h2f*)&wv1.z, h2v, a1e);
                a0o = dot2(*(h2f*)&wv0.w, h3, a0o);  a1o = dot2(*(h2f*)&wv1.w, h3, a1o);
            }
            #pragma unroll
            for (int jj = 3; jj < 31; ++jj) {
                uint4 hq = hp4[jj];
                h2f h0 = *(h2f*)&hq.x, h1 = *(h2f*)&hq.y, h2v = *(h2f*)&hq.z, h3 = *(h2f*)&hq.w;
                int p = 4 * jj - 12;
                a0e = dot2(w0r[p + 0], h0, a0e);  a1e = dot2(w1r[p + 0], h0, a1e);
                a0o = dot2(w0r[p + 1], h1, a0o);  a1o = dot2(w1r[p + 1], h1, a1o);
                a0e = dot2(w0r[p + 2], h2v, a0e); a1e = dot2(w1r[p + 2], h2v, a1e);
                a0o = dot2(w0r[p + 3], h3, a0o);  a1o = dot2(w1r[p + 3], h3, a1o);
            }
            {
                unsigned int hq = hp[124];
                h2f hv = *(h2f*)&hq;
                a0e = dot2(w0r[112], hv, a0e);
                a1e = dot2(w1r[112], hv, a1e);
            }
            a0 = a0e + a0o;
            a1 = a1e + a1o;
            if (t >= 250) {
                fo_lds[t - 250] = sigf(a0);
                fo_lds[250 + (t - 250)] = sigf(a1);
            }
        }
        __syncthreads();
        if (t < 250) {
            float iv = sigf(a0);
            float gv = tanhf(a1);
            float fv = fo_lds[t];
            float ov = fo_lds[250 + t];
            c = fv * c + iv * gv;
            float hn = ov * tanhf(c);
            out[tt * 250 + t] = hn;
            float hi = __shfl_down(hn, 1);
            if (!(t & 1)) {
                h2f pv; pv.x = (_Float16)hn; pv.y = (_Float16)hi;
                hp[t >> 1] = *(unsigned int*)&pv;
            }
        }
        px0 = n0; px1 = n1; tt = ttn;
        __syncthreads();
    }
}

// ---------------- 3) similarity cube with inline norms: 13 x 48 x 48 ----------------
__global__ void sim_kernel(const float* __restrict__ hs, float* __restrict__ sc)
{
    int p = blockIdx.x;
    int i = p / 48, jj = p % 48;
    const float* h1f = hs + ((size_t)0 * 48 + i) * 250;
    const float* h1b = hs + ((size_t)1 * 48 + i) * 250;
    const float* h2f = hs + ((size_t)2 * 48 + jj) * 250;
    const float* h2b = hs + ((size_t)3 * 48 + jj) * 250;
    int lane = threadIdx.x;
    float dff = 0.f, dbb = 0.f, dfb = 0.f, dbf = 0.f;
    float sfa = 0.f, sba = 0.f, caa = 0.f;
    float sfb = 0.f, sbb = 0.f, cbb = 0.f;
    for (int k = lane; k < 250; k += 64) {
        float af = h1f[k], ab = h1b[k], bf = h2f[k], bb = h2b[k];
        dff += af * bf; dbb += ab * bb; dfb += af * bb; dbf += ab * bf;
        sfa += af * af; sba += ab * ab; caa += af * ab;
        sfb += bf * bf; sbb += bb * bb; cbb += bf * bb;
    }
    #pragma unroll
    for (int o = 32; o; o >>= 1) {
        dff += __shfl_down(dff, o); dbb += __shfl_down(dbb, o);
        dfb += __shfl_down(dfb, o); dbf += __shfl_down(dbf, o);
        sfa += __shfl_down(sfa, o); sba += __shfl_down(sba, o);
        caa += __shfl_down(caa, o);
        sfb += __shfl_down(sfb, o); sbb += __shfl_down(sbb, o);
        cbb += __shfl_down(cbb, o);
    }
    if (lane == 0) {
        #define EMIT(basep, dotv, sa2, sb2)                                 \
        {                                                                   \
            float na = sqrtf(sa2), nbv = sqrtf(sb2);                        \
            float dv = (dotv);                                              \
            sc[(basep) * 2304 + p] = dv;                                    \
            sc[((basep) + 1) * 2304 + p] = dv / (na * nbv + 1e-8f);         \
            float d2 = fmaxf(na * na + nbv * nbv - 2.f * dv, 1e-12f);       \
            sc[((basep) + 2) * 2304 + p] = sqrtf(d2);                       \
        }
        EMIT(0, dff + dbb, sfa + sba, sfb + sbb);
        EMIT(3, dff, sfa, sfb);
        EMIT(6, dbb, sba, sbb);
        EMIT(9, dff + dfb + dbf + dbb, sfa + sba + 2.f * caa, sfb + sbb + 2.f * cbb);
        #undef EMIT
        // plane 12 is identically zero and skipped by conv1
    }
}

// ---------------- 4) greedy top-k: single wave per plane, register-resident sorted runs ----------------
__global__ void greedy_kernel(const float* __restrict__ sc, unsigned char* __restrict__ sel)
{
    __shared__ unsigned char selL[2304];
    int lane = threadIdx.x;
    int plane = 10 + blockIdx.x;

    u64 v[36];
    #pragma unroll
    for (int q = 0; q < 36; ++q) {
        int i = lane + 64 * q;
        unsigned int u = __float_as_uint(sc[plane * 2304 + i]);
        unsigned int ord = (u & 0x80000000u) ? ~u : (u | 0x80000000u);
        v[q] = ((u64)ord << 32) | (unsigned int)(4095 - i);
        selL[i] = 0;
    }

    #pragma unroll
    for (int a = 0; a < 35; ++a) {
        #pragma unroll
        for (int b = 0; b < 35 - a; ++b) {
            u64 lo = v[b] < v[b + 1] ? v[b] : v[b + 1];
            u64 hi = v[b] < v[b + 1] ? v[b + 1] : v[b];
            v[b] = hi; v[b + 1] = lo;
        }
    }
    __syncthreads();

    u64 m1 = 0, m2 = 0;
    for (int it = 0; it < 96; ++it) {
        u64 bv = v[0];
        #pragma unroll
        for (int o = 1; o < 64; o <<= 1) {
            u64 ov = __shfl_xor(bv, o);
            if (ov > bv) bv = ov;
        }
        int idx = 4095 - (int)(bv & 0xFFFFFFFFu);
        int p1 = idx / 48, p2 = idx % 48;
        bool ok = !((m1 >> p1) & 1) && !((m2 >> p2) & 1);
        if (ok) { m1 |= 1ull << p1; m2 |= 1ull << p2; }
        if (v[0] == bv) {
            if (ok) selL[idx] = 1;
            #pragma unroll
            for (int q = 0; q < 35; ++q) v[q] = v[q + 1];
            v[35] = 0;
        }
    }
    __syncthreads();
    for (int q = 0; q < 36; ++q) {
        int i = lane + 64 * q;
        sel[blockIdx.x * 2304 + i] = selL[i];
    }
}

// ---------------- 5) conv1 (12 planes ->128, 48x48) + fused focus mask + relu + pool2x2 ----------------
__global__ void conv1_pool_kernel(const float* __restrict__ sc, const unsigned char* __restrict__ sel,
                                  const float* __restrict__ w, const float* __restrict__ bias,
                                  float* __restrict__ out)
{
    __shared__ float tile[256];
    int co  = blockIdx.x / 9;
    int tl  = blockIdx.x % 9;
    int ty0 = (tl / 3) * 16, tx0 = (tl % 3) * 16;
    int tx = threadIdx.x % 16, ty = threadIdx.x / 16;
    int x = tx0 + tx, y = ty0 + ty;

    float mv[9];
    #pragma unroll
    for (int ky = 0; ky < 3; ++ky) {
        int iy = y + ky - 1;
        #pragma unroll
        for (int kx = 0; kx < 3; ++kx) {
            int ix = x + kx - 1;
            float mm = 0.f;
            if (iy >= 0 && iy < 48 && ix >= 0 && ix < 48) {
                int p = iy * 48 + ix;
                mm = (sel[p] | sel[2304 + p]) ? 1.0f : 0.1f;
            }
            mv[ky * 3 + kx] = mm;
        }
    }

    float acc = bias[co];
    const float* wco = w + (size_t)co * 13 * 9;
    for (int ci = 0; ci < 12; ++ci) {
        const float* inp = sc + (size_t)ci * 2304;
        const float* wp = wco + ci * 9;
        #pragma unroll
        for (int ky = 0; ky < 3; ++ky) {
            int iy = y + ky - 1;
            if (iy < 0 || iy >= 48) continue;
            #pragma unroll
            for (int kx = 0; kx < 3; ++kx) {
                int ix = x + kx - 1;
                if (ix < 0 || ix >= 48) continue;
                acc += inp[iy * 48 + ix] * mv[ky * 3 + kx] * wp[ky * 3 + kx];
            }
        }
    }
    tile[threadIdx.x] = acc > 0.f ? acc : 0.f;
    __syncthreads();
    if (threadIdx.x < 64) {
        int py = threadIdx.x / 8, px = threadIdx.x % 8;
        float a = tile[(py * 2) * 16 + px * 2];
        float b = tile[(py * 2) * 16 + px * 2 + 1];
        float cc = tile[(py * 2 + 1) * 16 + px * 2];
        float d = tile[(py * 2 + 1) * 16 + px * 2 + 1];
        float best = fmaxf(fmaxf(a, b), fmaxf(cc, d));
        out[(size_t)co * 576 + (ty0 / 2 + py) * 24 + (tx0 / 2 + px)] = best;
    }
}

// ---------------- 6) Cin-split conv3x3 + relu + pool (conv2..conv5) ----------------
__global__ void conv_cs_kernel(const float* __restrict__ in, const float* __restrict__ w,
                               const float* __restrict__ bias, float* __restrict__ out,
                               int Cin, int H, int W, int tileH, int tileW,
                               int cpc, int CC, int pk, int ps, int PHf, int PWf)
{
    extern __shared__ float sm[];          // P*CC partials + P results
    int P = tileH * tileW;
    int co = blockIdx.x;
    int ty0 = blockIdx.y * tileH, tx0 = blockIdx.z * tileW;
    int t = threadIdx.x;
    int pix = t % P, chunk = t / P;
    int y = ty0 + pix / tileW, x = tx0 + pix % tileW;
    int c0 = chunk * cpc;
    int c1 = c0 + cpc; if (c1 > Cin) c1 = Cin;

    float acc = 0.f;
    const float* wco = w + (size_t)co * Cin * 9;
    for (int ci = c0; ci < c1; ++ci) {
        const float* inp = in + (size_t)ci * H * W;
        const float* wp = wco + (size_t)ci * 9;
        #pragma unroll
        for (int ky = 0; ky < 3; ++ky) {
            int iy = y + ky - 1;
            if (iy < 0 || iy >= H) continue;
            const float* rowp = inp + iy * W;
            #pragma unroll
            for (int kx = 0; kx < 3; ++kx) {
                int ix = x + kx - 1;
                if (ix < 0 || ix >= W) continue;
                acc += rowp[ix] * wp[ky * 3 + kx];
            }
        }
    }
    sm[t] = acc;
    __syncthreads();
    float* res = sm + P * CC;
    if (chunk == 0) {
        float tot = bias[co];
        for (int cc2 = 0; cc2 < CC; ++cc2) tot += sm[pix + cc2 * P];
        res[pix] = tot > 0.f ? tot : 0.f;
    }
    __syncthreads();
    int pH = (tileH - pk) / ps + 1, pW = (tileW - pk) / ps + 1;
    if (t < pH * pW) {
        int py = t / pW, px = t % pW;
        float best = -INFINITY;
        for (int dy = 0; dy < pk; ++dy)
            for (int dx = 0; dx < pk; ++dx) {
                float v = res[(py * ps + dy) * tileW + (px * ps + dx)];
                best = v > best ? v : best;
            }
        out[((size_t)co * PHf + (ty0 / ps + py)) * PWf + (tx0 / ps + px)] = best;
    }
}

// ---------------- 7) head ----------------
__global__ void head_kernel(const float* __restrict__ feat,
                            const float* __restrict__ dnn_w, const float* __restrict__ dnn_b,
                            const float* __restrict__ out_w, const float* __restrict__ out_b,
                            float* __restrict__ out)
{
    __shared__ float y[128];
    __shared__ float logits[5];
    int j = threadIdx.x;
    float acc = dnn_b[j];
    for (int k = 0; k < 128; ++k) acc += feat[k] * dnn_w[j * 128 + k];
    y[j] = acc > 0.f ? acc : 0.f;
    __syncthreads();
    if (j < 5) {
        float a = out_b[j];
        for (int k = 0; k < 128; ++k) a += y[k] * out_w[j * 128 + k];
        logits[j] = a;
    }
    __syncthreads();
    if (j == 0) {
        float m = logits[0];
        for (int l = 1; l < 5; ++l) m = fmaxf(m, logits[l]);
        float s = 0.f;
        for (int l = 0; l < 5; ++l) s += expf(logits[l] - m);
        float lse = logf(s);
        for (int l = 0; l < 5; ++l) out[l] = logits[l] - m - lse;
    }
}

extern "C" void kernel_launch(void* const* d_in, const int* in_sizes, int n_in,
                              void* d_out, int out_size, void* d_ws, size_t ws_size,
                              hipStream_t stream)
{
    const int*   x1     = (const int*)d_in[0];
    const int*   x2     = (const int*)d_in[1];
    const float* emb    = (const float*)d_in[2];
    const float* w_ih_f = (const float*)d_in[3];
    const float* w_hh_f = (const float*)d_in[4];
    const float* b_f    = (const float*)d_in[5];
    const float* w_ih_b = (const float*)d_in[6];
    const float* w_hh_b = (const float*)d_in[7];
    const float* b_b    = (const float*)d_in[8];
    const float* c1_w   = (const float*)d_in[9];
    const float* c1_b   = (const float*)d_in[10];
    const float* c2_w   = (const float*)d_in[11];
    const float* c2_b   = (const float*)d_in[12];
    const float* c3_w   = (const float*)d_in[13];
    const float* c3_b   = (const float*)d_in[14];
    const float* c4_w   = (const float*)d_in[15];
    const float* c4_b   = (const float*)d_in[16];
    const float* c5_w   = (const float*)d_in[17];
    const float* c5_b   = (const float*)d_in[18];
    const float* dnn_w  = (const float*)d_in[19];
    const float* dnn_b  = (const float*)d_in[20];
    const float* out_w  = (const float*)d_in[21];
    const float* out_b  = (const float*)d_in[22];

    float* ws    = (float*)d_ws;
    float* xW    = ws + OFF_XW;
    float* hsb   = ws + OFF_HS;
    float* sc    = ws + OFF_SC;
    float* bufA  = ws + OFF_BUFA;
    float* bufB  = ws + OFF_BUFB;
    float* wihT  = ws + OFF_WIHT;
    unsigned int* wpk = (unsigned int*)(ws + OFF_WPK);
    unsigned char* sel = (unsigned char*)(ws + OFF_SEL);
    float* outp  = (float*)d_out;

    prep_kernel<<<dim3(32, 10, 3), dim3(32, 32), 0, stream>>>(
        w_ih_f, w_ih_b, w_hh_f, w_hh_b, wihT, wpk);
    embed_xw_kernel<<<192, 512, 0, stream>>>(x1, x2, emb, wihT, b_f, b_b, xW);
    lstm_kernel<<<4, 512, 0, stream>>>(xW, wpk, hsb);
    sim_kernel<<<2304, 64, 0, stream>>>(hsb, sc);
    greedy_kernel<<<2, 64, 0, stream>>>(sc, sel);

    // conv stack: 13x48x48 ->128x24x24 ->164x12x12 ->192x6x6 ->192x3x3 ->128
    conv1_pool_kernel<<<128 * 9, 256, 0, stream>>>(sc, sel, c1_w, c1_b, bufA);
    conv_cs_kernel<<<dim3(164, 2, 2), 576, (576 + 144) * 4, stream>>>(
        bufA, c2_w, c2_b, bufB, 128, 24, 24, 12, 12, 32, 4, 2, 2, 12, 12);
    conv_cs_kernel<<<dim3(192, 1, 1), 576, (576 + 144) * 4, stream>>>(
        bufB, c3_w, c3_b, bufA, 164, 12, 12, 12, 12, 41, 4, 2, 2, 6, 6);
    conv_cs_kernel<<<dim3(192, 1, 1), 576, (576 + 36) * 4, stream>>>(
        bufA, c4_w, c4_b, bufB, 192, 6, 6, 6, 6, 12, 16, 2, 2, 3, 3);
    conv_cs_kernel<<<dim3(128, 1, 1), 576, (576 + 9) * 4, stream>>>(
        bufB, c5_w, c5_b, bufA, 192, 3, 3, 3, 3, 3, 64, 3, 1, 1, 1);

    head_kernel<<<1, 128, 0, stream>>>(bufA, dnn_w, dnn_b, out_w, out_b, outp);
}